// Round 2
// baseline (152.330 us; speedup 1.0000x reference)
//
#include <hip/hip_runtime.h>

#define NPIX 65536
#define NB 8
#define NN 64
#define KK 32
#define LOG2E 1.4426950408889634f

__device__ __forceinline__ float rcpf(float x) { return __builtin_amdgcn_rcpf(x); }
__device__ __forceinline__ float exp2_fast(float x) { float r; asm("v_exp_f32 %0, %1" : "=v"(r) : "v"(x)); return r; }
__device__ __forceinline__ float log2_fast(float x) { float r; asm("v_log_f32 %0, %1" : "=v"(r) : "v"(x)); return r; }

// Phase 1: fc[b, pix] = 1 - S2/(S1+1e-5).  One thread = one pixel.
// Per-(b,n) params folded: a_n = exp2(dx^2*gx + dy^2*gy + log2(cf)) * rcp(1 + exp2(sdot))
// where sdot = proto . (mask * -log2e)  => exp2(sdot) = exp(-s).
__global__ __launch_bounds__(256, 8) void k_phase1(
    const float* __restrict__ loc,    // [B,N,4]
    const float* __restrict__ masks,  // [B,N,K]
    const float* __restrict__ proto,  // [B,H,W,K]
    const float* __restrict__ conf,   // [B,N]
    float* __restrict__ fcb)          // [B, NPIX]
{
    __shared__ float4 smask[NN * 8];  // masks pre-scaled by -log2e (8 KB)
    __shared__ float4 sprm[NN];       // cx, cy, gx, gy
    __shared__ float  slc[NN];        // log2(conf)

    const int b    = blockIdx.x >> 8;       // wave-uniform
    const int tile = blockIdx.x & 255;
    const int tid  = threadIdx.x;

    // --- prep: stage scaled masks + folded loc params into LDS ---
    {
        const float4* m4 = (const float4*)(masks + (size_t)b * NN * KK);
        float4 v0 = m4[tid], v1 = m4[tid + 256];
        v0.x *= -LOG2E; v0.y *= -LOG2E; v0.z *= -LOG2E; v0.w *= -LOG2E;
        v1.x *= -LOG2E; v1.y *= -LOG2E; v1.z *= -LOG2E; v1.w *= -LOG2E;
        smask[tid] = v0; smask[tid + 256] = v1;
        if (tid < NN) {
            float4 L = ((const float4*)loc)[b * NN + tid];
            float isx = rcpf(L.z), isy = rcpf(L.w);
            // -0.5 * log2(e) = -0.72134752
            sprm[tid] = make_float4(L.x, L.y, -0.72134752f * isx * isx,
                                              -0.72134752f * isy * isy);
            slc[tid] = log2_fast(conf[b * NN + tid]);
        }
    }
    __syncthreads();

    const int pix = tile * 256 + tid;
    const float inv = 1.0f / 256.0f;
    const float fx = ((pix & 255) + 0.5f) * inv;
    const float fy = ((pix >> 8) + 0.5f) * inv;

    const float4* p4 = (const float4*)(proto + ((size_t)b * NPIX + pix) * KK);
    float4 A[8];
#pragma unroll
    for (int j = 0; j < 8; ++j) A[j] = p4[j];

    float S1 = 0.f, S2 = 0.f;
    for (int n = 0; n < NN; ++n) {
        const float4 P = sprm[n];
        const float lc = slc[n];
        float sa = 0.f, sb = 0.f, sc = 0.f, sd = 0.f;  // 4 indep FMA chains
#pragma unroll
        for (int j = 0; j < 8; j += 4) {
            float4 m0 = smask[n * 8 + j],     m1 = smask[n * 8 + j + 1];
            float4 m2 = smask[n * 8 + j + 2], m3 = smask[n * 8 + j + 3];
            sa = fmaf(A[j  ].w, m0.w, fmaf(A[j  ].z, m0.z, fmaf(A[j  ].y, m0.y, fmaf(A[j  ].x, m0.x, sa))));
            sb = fmaf(A[j+1].w, m1.w, fmaf(A[j+1].z, m1.z, fmaf(A[j+1].y, m1.y, fmaf(A[j+1].x, m1.x, sb))));
            sc = fmaf(A[j+2].w, m2.w, fmaf(A[j+2].z, m2.z, fmaf(A[j+2].y, m2.y, fmaf(A[j+2].x, m2.x, sc))));
            sd = fmaf(A[j+3].w, m3.w, fmaf(A[j+3].z, m3.z, fmaf(A[j+3].y, m3.y, fmaf(A[j+3].x, m3.x, sd))));
        }
        const float s = (sa + sb) + (sc + sd);           // = -log2e * (proto.mask)
        const float dxu = fx - P.x, dyu = fy - P.y;
        const float t = fmaf(dxu * dxu, P.z, fmaf(dyu * dyu, P.w, lc));
        const float g = exp2_fast(t);                    // cf * gauss
        const float sig = rcpf(1.0f + exp2_fast(s));     // sigmoid(proto.mask)
        const float a = g * sig;
        S1 += a;
        S2 = fmaf(a, a, S2);
    }
    fcb[(size_t)b * NPIX + pix] = 1.0f - S2 * rcpf(S1 + 1e-5f);
}

// Phase 2: weighted-variance sum -> scalar. Split by channel for parallelism.
__global__ __launch_bounds__(256) void k_phase2(
    const float* __restrict__ original,  // [B,3,H,W]
    const float* __restrict__ fcb,       // [B, NPIX]
    float* __restrict__ out)
{
    const int c   = blockIdx.x >> 8;          // 0..2
    const int pix = (blockIdx.x & 255) * 256 + threadIdx.x;

    float f[NB];
    float tot = 0.f;
#pragma unroll
    for (int b = 0; b < NB; ++b) { f[b] = fcb[(size_t)b * NPIX + pix]; tot += f[b]; }

    float o[NB];
    float wm = 0.f;
#pragma unroll
    for (int b = 0; b < NB; ++b) {
        o[b] = original[((size_t)(b * 3 + c)) * NPIX + pix];
        wm = fmaf(o[b], f[b], wm);
    }
    float part = 0.f;
#pragma unroll
    for (int b = 0; b < NB; ++b) {
        float d = o[b] - wm;
        part = fmaf(d * d, f[b], part);
    }
    part *= rcpf(tot);

#pragma unroll
    for (int off = 32; off > 0; off >>= 1) part += __shfl_down(part, off);
    __shared__ float sred[4];
    if ((threadIdx.x & 63) == 0) sred[threadIdx.x >> 6] = part;
    __syncthreads();
    if (threadIdx.x == 0) atomicAdd(out, sred[0] + sred[1] + sred[2] + sred[3]);
}

// Fallback: fully fused, no workspace needed (used only if ws_size too small).
__global__ __launch_bounds__(256) void k_fused(
    const float* __restrict__ original, const float* __restrict__ loc,
    const float* __restrict__ masks, const float* __restrict__ proto,
    const float* __restrict__ conf, float* __restrict__ out)
{
    const int pix = blockIdx.x * 256 + threadIdx.x;
    const float inv = 1.0f / 256.0f;
    const float fx = ((pix & 255) + 0.5f) * inv;
    const float fy = ((pix >> 8) + 0.5f) * inv;

    float f[NB];
    for (int b = 0; b < NB; ++b) {
        const float4* p4 = (const float4*)(proto + ((size_t)b * NPIX + pix) * KK);
        float4 A[8];
#pragma unroll
        for (int j = 0; j < 8; ++j) A[j] = p4[j];
        const float4* m4 = (const float4*)(masks + (size_t)b * NN * KK);
        const float4* l4 = (const float4*)(loc + (size_t)b * NN * 4);
        const float*  cf = conf + b * NN;
        float S1 = 0.f, S2 = 0.f;
        for (int n = 0; n < NN; ++n) {
            float sa = 0.f, sb = 0.f;
#pragma unroll
            for (int j = 0; j < 8; j += 2) {
                float4 m = m4[n * 8 + j];
                sa = fmaf(A[j].w, m.w, fmaf(A[j].z, m.z, fmaf(A[j].y, m.y, fmaf(A[j].x, m.x, sa))));
                float4 q = m4[n * 8 + j + 1];
                sb = fmaf(A[j+1].w, q.w, fmaf(A[j+1].z, q.z, fmaf(A[j+1].y, q.y, fmaf(A[j+1].x, q.x, sb))));
            }
            const float4 L = l4[n];
            float isx = rcpf(L.z), isy = rcpf(L.w);
            float dx = (fx - L.x) * isx, dy = (fy - L.y) * isy;
            float g = __expf(-0.5f * fmaf(dx, dx, dy * dy));
            float a = g * rcpf(1.0f + __expf(-(sa + sb))) * cf[n];
            S1 += a;
            S2 = fmaf(a, a, S2);
        }
        f[b] = 1.0f - S2 * rcpf(S1 + 1e-5f);
    }
    float tot = 0.f;
#pragma unroll
    for (int b = 0; b < NB; ++b) tot += f[b];
    float part = 0.f;
#pragma unroll
    for (int c = 0; c < 3; ++c) {
        float o[NB];
        float wm = 0.f;
#pragma unroll
        for (int b = 0; b < NB; ++b) {
            o[b] = original[((size_t)(b * 3 + c)) * NPIX + pix];
            wm = fmaf(o[b], f[b], wm);
        }
#pragma unroll
        for (int b = 0; b < NB; ++b) {
            float d = o[b] - wm;
            part = fmaf(d * d, f[b], part);
        }
    }
    part *= rcpf(tot);

#pragma unroll
    for (int off = 32; off > 0; off >>= 1) part += __shfl_down(part, off);
    __shared__ float sred[4];
    if ((threadIdx.x & 63) == 0) sred[threadIdx.x >> 6] = part;
    __syncthreads();
    if (threadIdx.x == 0) atomicAdd(out, sred[0] + sred[1] + sred[2] + sred[3]);
}

extern "C" void kernel_launch(void* const* d_in, const int* in_sizes, int n_in,
                              void* d_out, int out_size, void* d_ws, size_t ws_size,
                              hipStream_t stream) {
    const float* original = (const float*)d_in[0];
    const float* loc      = (const float*)d_in[1];
    const float* masks    = (const float*)d_in[2];
    const float* proto    = (const float*)d_in[3];
    const float* conf     = (const float*)d_in[4];
    float* out = (float*)d_out;

    hipMemsetAsync(out, 0, sizeof(float), stream);

    const size_t fc_bytes = (size_t)NB * NPIX * sizeof(float);
    if (ws_size >= fc_bytes) {
        float* fcb = (float*)d_ws;
        k_phase1<<<NB * (NPIX / 256), 256, 0, stream>>>(loc, masks, proto, conf, fcb);
        k_phase2<<<3 * (NPIX / 256), 256, 0, stream>>>(original, fcb, out);
    } else {
        k_fused<<<NPIX / 256, 256, 0, stream>>>(original, loc, masks, proto, conf, out);
    }
}

// Round 4
// 60.232 us; speedup vs baseline: 2.5291x; 2.5291x over previous
//
#include <hip/hip_runtime.h>

#define NPIX 65536
#define NB 8
#define NN 64
#define KK 32
#define LOG2E 1.4426950408889634f

typedef _Float16 half2v __attribute__((ext_vector_type(2)));

__device__ __forceinline__ float rcpf(float x) { return __builtin_amdgcn_rcpf(x); }
__device__ __forceinline__ float exp2_fast(float x) { float r; asm("v_exp_f32 %0, %1" : "=v"(r) : "v"(x)); return r; }
__device__ __forceinline__ float log2_fast(float x) { float r; asm("v_log_f32 %0, %1" : "=v"(r) : "v"(x)); return r; }

#if __has_builtin(__builtin_amdgcn_fdot2)
__device__ __forceinline__ float fdot2(half2v a, half2v b, float c) {
    return __builtin_amdgcn_fdot2(a, b, c, false);
}
#else
__device__ __forceinline__ float fdot2(half2v a, half2v b, float c) {
    return fmaf((float)a[1], (float)b[1], fmaf((float)a[0], (float)b[0], c));
}
#endif

// Phase 1: fc[b, pix] = 1 - S2/(S1+1e-5). One thread = one pixel.
// Block = one image row of one batch (fy, dy uniform per block).
// a_n = exp2(gx*dx^2 + ey_n) * rcp(1 + exp2(s)),  s = proto . (mask * -log2e)
// ey_n = gy*dy^2 + log2(conf_n) precomputed per block; n skipped if ey < -35
// (a <= 3e-11, negligible vs the 1e-5 denominator floor).
__global__ __launch_bounds__(256) void k_phase1(
    const float* __restrict__ loc,    // [B,N,4]
    const float* __restrict__ masks,  // [B,N,K]
    const float* __restrict__ proto,  // [B,H,W,K]
    const float* __restrict__ conf,   // [B,N]
    float* __restrict__ fcb)          // [B, NPIX]
{
    __shared__ half2v smask[NN * KK / 2];  // masks * -log2e, f16 pairs (4 KB)
    __shared__ float4 sprm[NN];            // cx, gx, ey, pad

    const int b   = blockIdx.x >> 8;       // wave-uniform
    const int row = blockIdx.x & 255;
    const int tid = threadIdx.x;

    const float inv = 1.0f / 256.0f;
    const float fy  = (row + 0.5f) * inv;

    // --- prep: stage scaled f16 masks + folded per-n params into LDS ---
    {
        const float4* m4 = (const float4*)(masks + (size_t)b * NN * KK);
        float4 u0 = m4[tid * 2], u1 = m4[tid * 2 + 1];
        half2v h0, h1, h2, h3;
        h0[0] = (_Float16)(u0.x * -LOG2E); h0[1] = (_Float16)(u0.y * -LOG2E);
        h1[0] = (_Float16)(u0.z * -LOG2E); h1[1] = (_Float16)(u0.w * -LOG2E);
        h2[0] = (_Float16)(u1.x * -LOG2E); h2[1] = (_Float16)(u1.y * -LOG2E);
        h3[0] = (_Float16)(u1.z * -LOG2E); h3[1] = (_Float16)(u1.w * -LOG2E);
        smask[tid * 4]     = h0;
        smask[tid * 4 + 1] = h1;
        smask[tid * 4 + 2] = h2;
        smask[tid * 4 + 3] = h3;
        if (tid < NN) {
            float4 L = ((const float4*)loc)[b * NN + tid];
            float isx = rcpf(L.z), isy = rcpf(L.w);
            // -0.5 * log2(e) = -0.72134752
            float gx = -0.72134752f * isx * isx;
            float gy = -0.72134752f * isy * isy;
            float dy = fy - L.y;
            float ey = fmaf(dy * dy, gy, log2_fast(conf[b * NN + tid]));
            sprm[tid] = make_float4(L.x, gx, ey, 0.f);
        }
    }
    __syncthreads();

    const int pix = row * 256 + tid;
    const float fx = (tid + 0.5f) * inv;

    // proto row -> f16 pairs in registers (16 VGPRs)
    const float4* p4 = (const float4*)(proto + ((size_t)b * NPIX + pix) * KK);
    half2v A[16];
#pragma unroll
    for (int j = 0; j < 8; ++j) {
        float4 v = p4[j];
        half2v ha, hb;
        ha[0] = (_Float16)v.x; ha[1] = (_Float16)v.y;
        hb[0] = (_Float16)v.z; hb[1] = (_Float16)v.w;
        A[2 * j] = ha; A[2 * j + 1] = hb;
    }

    float S1 = 0.f, S2 = 0.f;
    for (int n = 0; n < NN; ++n) {
        const float4 P = sprm[n];
        if (P.z > -35.f) {              // wave-uniform skip of negligible priors
            const half2v* mk = smask + n * 16;
            float s0 = 0.f, s1 = 0.f;   // 2 indep dot chains
#pragma unroll
            for (int j = 0; j < 16; j += 2) {
                s0 = fdot2(A[j],     mk[j],     s0);
                s1 = fdot2(A[j + 1], mk[j + 1], s1);
            }
            float dxu = fx - P.x;
            float e   = fmaf(dxu * dxu, P.y, P.z);
            float g   = exp2_fast(e);                  // conf * gauss
            float sg  = rcpf(1.0f + exp2_fast(s0 + s1));  // sigmoid(proto.mask)
            float a   = g * sg;
            S1 += a;
            S2 = fmaf(a, a, S2);
        }
    }
    fcb[(size_t)b * NPIX + pix] = 1.0f - S2 * rcpf(S1 + 1e-5f);
}

// Phase 2: weighted-variance sum -> scalar. Split by channel for parallelism.
__global__ __launch_bounds__(256) void k_phase2(
    const float* __restrict__ original,  // [B,3,H,W]
    const float* __restrict__ fcb,       // [B, NPIX]
    float* __restrict__ out)
{
    const int c   = blockIdx.x >> 8;          // 0..2
    const int pix = (blockIdx.x & 255) * 256 + threadIdx.x;

    float f[NB];
    float tot = 0.f;
#pragma unroll
    for (int b = 0; b < NB; ++b) { f[b] = fcb[(size_t)b * NPIX + pix]; tot += f[b]; }

    float o[NB];
    float wm = 0.f;
#pragma unroll
    for (int b = 0; b < NB; ++b) {
        o[b] = original[((size_t)(b * 3 + c)) * NPIX + pix];
        wm = fmaf(o[b], f[b], wm);
    }
    float part = 0.f;
#pragma unroll
    for (int b = 0; b < NB; ++b) {
        float d = o[b] - wm;
        part = fmaf(d * d, f[b], part);
    }
    part *= rcpf(tot);

#pragma unroll
    for (int off = 32; off > 0; off >>= 1) part += __shfl_down(part, off);
    __shared__ float sred[4];
    if ((threadIdx.x & 63) == 0) sred[threadIdx.x >> 6] = part;
    __syncthreads();
    if (threadIdx.x == 0) atomicAdd(out, sred[0] + sred[1] + sred[2] + sred[3]);
}

// Fallback: fully fused scalar path, only if ws_size too small (shouldn't happen).
__global__ __launch_bounds__(256) void k_fused(
    const float* __restrict__ original, const float* __restrict__ loc,
    const float* __restrict__ masks, const float* __restrict__ proto,
    const float* __restrict__ conf, float* __restrict__ out)
{
    const int pix = blockIdx.x * 256 + threadIdx.x;
    const float inv = 1.0f / 256.0f;
    const float fx = ((pix & 255) + 0.5f) * inv;
    const float fy = ((pix >> 8) + 0.5f) * inv;

    float f[NB];
    for (int b = 0; b < NB; ++b) {
        const float4* p4 = (const float4*)(proto + ((size_t)b * NPIX + pix) * KK);
        const float4* m4 = (const float4*)(masks + (size_t)b * NN * KK);
        const float4* l4 = (const float4*)(loc + (size_t)b * NN * 4);
        const float*  cf = conf + b * NN;
        float S1 = 0.f, S2 = 0.f;
        for (int n = 0; n < NN; ++n) {
            float sa = 0.f;
#pragma unroll
            for (int j = 0; j < 8; ++j) {
                float4 A = p4[j], m = m4[n * 8 + j];
                sa = fmaf(A.w, m.w, fmaf(A.z, m.z, fmaf(A.y, m.y, fmaf(A.x, m.x, sa))));
            }
            const float4 L = l4[n];
            float isx = rcpf(L.z), isy = rcpf(L.w);
            float dx = (fx - L.x) * isx, dy = (fy - L.y) * isy;
            float g = __expf(-0.5f * fmaf(dx, dx, dy * dy));
            float a = g * rcpf(1.0f + __expf(-sa)) * cf[n];
            S1 += a;
            S2 = fmaf(a, a, S2);
        }
        f[b] = 1.0f - S2 * rcpf(S1 + 1e-5f);
    }
    float tot = 0.f;
#pragma unroll
    for (int b = 0; b < NB; ++b) tot += f[b];
    float part = 0.f;
#pragma unroll
    for (int c = 0; c < 3; ++c) {
        float o[NB];
        float wm = 0.f;
#pragma unroll
        for (int b = 0; b < NB; ++b) {
            o[b] = original[((size_t)(b * 3 + c)) * NPIX + pix];
            wm = fmaf(o[b], f[b], wm);
        }
#pragma unroll
        for (int b = 0; b < NB; ++b) {
            float d = o[b] - wm;
            part = fmaf(d * d, f[b], part);
        }
    }
    part *= rcpf(tot);

#pragma unroll
    for (int off = 32; off > 0; off >>= 1) part += __shfl_down(part, off);
    __shared__ float sred[4];
    if ((threadIdx.x & 63) == 0) sred[threadIdx.x >> 6] = part;
    __syncthreads();
    if (threadIdx.x == 0) atomicAdd(out, sred[0] + sred[1] + sred[2] + sred[3]);
}

extern "C" void kernel_launch(void* const* d_in, const int* in_sizes, int n_in,
                              void* d_out, int out_size, void* d_ws, size_t ws_size,
                              hipStream_t stream) {
    const float* original = (const float*)d_in[0];
    const float* loc      = (const float*)d_in[1];
    const float* masks    = (const float*)d_in[2];
    const float* proto    = (const float*)d_in[3];
    const float* conf     = (const float*)d_in[4];
    float* out = (float*)d_out;

    hipMemsetAsync(out, 0, sizeof(float), stream);

    const size_t fc_bytes = (size_t)NB * NPIX * sizeof(float);
    if (ws_size >= fc_bytes) {
        float* fcb = (float*)d_ws;
        k_phase1<<<NB * (NPIX / 256), 256, 0, stream>>>(loc, masks, proto, conf, fcb);
        k_phase2<<<3 * (NPIX / 256), 256, 0, stream>>>(original, fcb, out);
    } else {
        k_fused<<<NPIX / 256, 256, 0, stream>>>(original, loc, masks, proto, conf, out);
    }
}

// Round 5
// 51.813 us; speedup vs baseline: 2.9400x; 1.1625x over previous
//
#include <hip/hip_runtime.h>

#define NPIX 65536
#define NB 8
#define NN 64
#define KK 32
#define LOG2E 1.4426950408889634f

typedef _Float16 half2v __attribute__((ext_vector_type(2)));

__device__ __forceinline__ float rcpf(float x) { return __builtin_amdgcn_rcpf(x); }
__device__ __forceinline__ float exp2_fast(float x) { float r; asm("v_exp_f32 %0, %1" : "=v"(r) : "v"(x)); return r; }
__device__ __forceinline__ float log2_fast(float x) { float r; asm("v_log_f32 %0, %1" : "=v"(r) : "v"(x)); return r; }

#if __has_builtin(__builtin_amdgcn_fdot2)
__device__ __forceinline__ float fdot2(half2v a, half2v b, float c) {
    return __builtin_amdgcn_fdot2(a, b, c, false);
}
#else
__device__ __forceinline__ float fdot2(half2v a, half2v b, float c) {
    return fmaf((float)a[1], (float)b[1], fmaf((float)a[0], (float)b[0], c));
}
#endif

// Phase 1: fc[b, pix] = 1 - S2/(S1+1e-5).
// Block = 128 threads = one image row of one batch; each thread does pixels
// (tid) and (tid+128) of that row -> ey (row term) shared, per-n LDS reads
// amortized over 2 pixels, 4 independent dot chains + 2 eval chains.
// No skip branch (mean active fraction ~93%; branch was blocking LDS pipelining).
__global__ __launch_bounds__(128) void k_phase1(
    const float* __restrict__ loc,    // [B,N,4]
    const float* __restrict__ masks,  // [B,N,K]
    const float* __restrict__ proto,  // [B,H,W,K]
    const float* __restrict__ conf,   // [B,N]
    float* __restrict__ fcb)          // [B, NPIX]
{
    __shared__ half2v smask[NN * 16];  // masks * -log2e as f16 pairs (4 KB)
    __shared__ float4 sprm[NN];        // cx, gx, ey, pad

    const int b   = blockIdx.x >> 8;   // wave-uniform
    const int row = blockIdx.x & 255;
    const int tid = threadIdx.x;

    const float inv = 1.0f / 256.0f;
    const float fy  = (row + 0.5f) * inv;

    // --- stage scaled f16 masks + folded per-n params into LDS ---
    {
        const float4* m4 = (const float4*)(masks + (size_t)b * NN * KK);
#pragma unroll
        for (int q = 0; q < 4; ++q) {
            float4 u = m4[tid * 4 + q];
            half2v h0, h1;
            h0[0] = (_Float16)(u.x * -LOG2E); h0[1] = (_Float16)(u.y * -LOG2E);
            h1[0] = (_Float16)(u.z * -LOG2E); h1[1] = (_Float16)(u.w * -LOG2E);
            smask[tid * 8 + q * 2]     = h0;
            smask[tid * 8 + q * 2 + 1] = h1;
        }
        if (tid < NN) {
            float4 L = ((const float4*)loc)[b * NN + tid];
            float isx = rcpf(L.z), isy = rcpf(L.w);
            // -0.5 * log2(e) = -0.72134752
            float gx = -0.72134752f * isx * isx;
            float gy = -0.72134752f * isy * isy;
            float dy = fy - L.y;
            float ey = fmaf(dy * dy, gy, log2_fast(conf[b * NN + tid]));
            sprm[tid] = make_float4(L.x, gx, ey, 0.f);
        }
    }
    __syncthreads();

    const int pix0 = row * 256 + tid;
    const int pix1 = pix0 + 128;
    const float fx0 = (tid + 0.5f) * inv;
    const float fx1 = (tid + 128 + 0.5f) * inv;

    // both proto rows -> f16 pairs in registers (32 VGPRs)
    half2v A0[16], A1[16];
    {
        const float4* p0 = (const float4*)(proto + ((size_t)b * NPIX + pix0) * KK);
        const float4* p1 = (const float4*)(proto + ((size_t)b * NPIX + pix1) * KK);
#pragma unroll
        for (int j = 0; j < 8; ++j) {
            float4 v = p0[j];
            half2v ha, hb;
            ha[0] = (_Float16)v.x; ha[1] = (_Float16)v.y;
            hb[0] = (_Float16)v.z; hb[1] = (_Float16)v.w;
            A0[2 * j] = ha; A0[2 * j + 1] = hb;
        }
#pragma unroll
        for (int j = 0; j < 8; ++j) {
            float4 v = p1[j];
            half2v ha, hb;
            ha[0] = (_Float16)v.x; ha[1] = (_Float16)v.y;
            hb[0] = (_Float16)v.z; hb[1] = (_Float16)v.w;
            A1[2 * j] = ha; A1[2 * j + 1] = hb;
        }
    }

    float S10 = 0.f, S20 = 0.f, S11 = 0.f, S21 = 0.f;
#pragma unroll 2
    for (int n = 0; n < NN; ++n) {
        const float4 P = sprm[n];
        const half2v* mk = smask + n * 16;
        float s0a = 0.f, s0b = 0.f, s1a = 0.f, s1b = 0.f;  // 4 indep dot chains
#pragma unroll
        for (int j = 0; j < 16; j += 2) {
            half2v m0 = mk[j], m1 = mk[j + 1];
            s0a = fdot2(A0[j],     m0, s0a);
            s0b = fdot2(A0[j + 1], m1, s0b);
            s1a = fdot2(A1[j],     m0, s1a);
            s1b = fdot2(A1[j + 1], m1, s1b);
        }
        // eval pixel 0
        float dx0 = fx0 - P.x;
        float e0  = fmaf(dx0 * dx0, P.y, P.z);
        float g0  = exp2_fast(e0);                    // conf * gauss
        float sg0 = rcpf(1.0f + exp2_fast(s0a + s0b));
        float a0  = g0 * sg0;
        S10 += a0;
        S20 = fmaf(a0, a0, S20);
        // eval pixel 1
        float dx1 = fx1 - P.x;
        float e1  = fmaf(dx1 * dx1, P.y, P.z);
        float g1  = exp2_fast(e1);
        float sg1 = rcpf(1.0f + exp2_fast(s1a + s1b));
        float a1  = g1 * sg1;
        S11 += a1;
        S21 = fmaf(a1, a1, S21);
    }
    fcb[(size_t)b * NPIX + pix0] = 1.0f - S20 * rcpf(S10 + 1e-5f);
    fcb[(size_t)b * NPIX + pix1] = 1.0f - S21 * rcpf(S11 + 1e-5f);
}

// Phase 2: weighted-variance sum -> scalar. One thread = one pixel, all 3
// channels (fcb read once; total traffic fcb 2MB + original 6.3MB).
__global__ __launch_bounds__(256) void k_phase2(
    const float* __restrict__ original,  // [B,3,H,W]
    const float* __restrict__ fcb,       // [B, NPIX]
    float* __restrict__ out)
{
    const int pix = blockIdx.x * 256 + threadIdx.x;

    float f[NB];
    float tot = 0.f;
#pragma unroll
    for (int b = 0; b < NB; ++b) { f[b] = fcb[(size_t)b * NPIX + pix]; tot += f[b]; }

    float part = 0.f;
#pragma unroll
    for (int c = 0; c < 3; ++c) {
        float o[NB];
        float wm = 0.f;
#pragma unroll
        for (int b = 0; b < NB; ++b) {
            o[b] = original[((size_t)(b * 3 + c)) * NPIX + pix];
            wm = fmaf(o[b], f[b], wm);
        }
#pragma unroll
        for (int b = 0; b < NB; ++b) {
            float d = o[b] - wm;
            part = fmaf(d * d, f[b], part);
        }
    }
    part *= rcpf(tot);

#pragma unroll
    for (int off = 32; off > 0; off >>= 1) part += __shfl_down(part, off);
    __shared__ float sred[4];
    if ((threadIdx.x & 63) == 0) sred[threadIdx.x >> 6] = part;
    __syncthreads();
    if (threadIdx.x == 0) atomicAdd(out, sred[0] + sred[1] + sred[2] + sred[3]);
}

// Fallback: fully fused scalar path, only if ws_size too small (shouldn't happen).
__global__ __launch_bounds__(256) void k_fused(
    const float* __restrict__ original, const float* __restrict__ loc,
    const float* __restrict__ masks, const float* __restrict__ proto,
    const float* __restrict__ conf, float* __restrict__ out)
{
    const int pix = blockIdx.x * 256 + threadIdx.x;
    const float inv = 1.0f / 256.0f;
    const float fx = ((pix & 255) + 0.5f) * inv;
    const float fy = ((pix >> 8) + 0.5f) * inv;

    float f[NB];
    for (int b = 0; b < NB; ++b) {
        const float4* p4 = (const float4*)(proto + ((size_t)b * NPIX + pix) * KK);
        const float4* m4 = (const float4*)(masks + (size_t)b * NN * KK);
        const float4* l4 = (const float4*)(loc + (size_t)b * NN * 4);
        const float*  cf = conf + b * NN;
        float S1 = 0.f, S2 = 0.f;
        for (int n = 0; n < NN; ++n) {
            float sa = 0.f;
#pragma unroll
            for (int j = 0; j < 8; ++j) {
                float4 A = p4[j], m = m4[n * 8 + j];
                sa = fmaf(A.w, m.w, fmaf(A.z, m.z, fmaf(A.y, m.y, fmaf(A.x, m.x, sa))));
            }
            const float4 L = l4[n];
            float isx = rcpf(L.z), isy = rcpf(L.w);
            float dx = (fx - L.x) * isx, dy = (fy - L.y) * isy;
            float g = __expf(-0.5f * fmaf(dx, dx, dy * dy));
            float a = g * rcpf(1.0f + __expf(-sa)) * cf[n];
            S1 += a;
            S2 = fmaf(a, a, S2);
        }
        f[b] = 1.0f - S2 * rcpf(S1 + 1e-5f);
    }
    float tot = 0.f;
#pragma unroll
    for (int b = 0; b < NB; ++b) tot += f[b];
    float part = 0.f;
#pragma unroll
    for (int c = 0; c < 3; ++c) {
        float o[NB];
        float wm = 0.f;
#pragma unroll
        for (int b = 0; b < NB; ++b) {
            o[b] = original[((size_t)(b * 3 + c)) * NPIX + pix];
            wm = fmaf(o[b], f[b], wm);
        }
#pragma unroll
        for (int b = 0; b < NB; ++b) {
            float d = o[b] - wm;
            part = fmaf(d * d, f[b], part);
        }
    }
    part *= rcpf(tot);

#pragma unroll
    for (int off = 32; off > 0; off >>= 1) part += __shfl_down(part, off);
    __shared__ float sred[4];
    if ((threadIdx.x & 63) == 0) sred[threadIdx.x >> 6] = part;
    __syncthreads();
    if (threadIdx.x == 0) atomicAdd(out, sred[0] + sred[1] + sred[2] + sred[3]);
}

extern "C" void kernel_launch(void* const* d_in, const int* in_sizes, int n_in,
                              void* d_out, int out_size, void* d_ws, size_t ws_size,
                              hipStream_t stream) {
    const float* original = (const float*)d_in[0];
    const float* loc      = (const float*)d_in[1];
    const float* masks    = (const float*)d_in[2];
    const float* proto    = (const float*)d_in[3];
    const float* conf     = (const float*)d_in[4];
    float* out = (float*)d_out;

    hipMemsetAsync(out, 0, sizeof(float), stream);

    const size_t fc_bytes = (size_t)NB * NPIX * sizeof(float);
    if (ws_size >= fc_bytes) {
        float* fcb = (float*)d_ws;
        k_phase1<<<NB * 256, 128, 0, stream>>>(loc, masks, proto, conf, fcb);
        k_phase2<<<NPIX / 256, 256, 0, stream>>>(original, fcb, out);
    } else {
        k_fused<<<NPIX / 256, 256, 0, stream>>>(original, loc, masks, proto, conf, out);
    }
}